// Round 2
// baseline (778.290 us; speedup 1.0000x reference)
//
#include <hip/hip_runtime.h>
#include <math.h>

#define Bn   4
#define CIN  128
#define Hh   64
#define Ww   64
#define HW   4096
#define CMID 64
#define KOC  100      // (scale*k_up)^2
#define H2   128
#define W2d  128
#define HW2  16384
#define KUP  5
#define BN_EPS 1e-5f

// ---------------- Kernel A: 1x1 conv + BN(eval) + SiLU -> W1 [B][CMID][H][W] fp32
__global__ __launch_bounds__(256) void comp_kernel(
    const float* __restrict__ X,
    const float* __restrict__ cw,
    const float* __restrict__ cg,
    const float* __restrict__ cb,
    float* __restrict__ W1)
{
    int idx = blockIdx.x * blockDim.x + threadIdx.x;   // ((b*CMID+co)*HW + pix)
    int pix = idx & (HW - 1);
    int t   = idx >> 12;
    int co  = t & (CMID - 1);
    int b   = t >> 6;

    const float* xb = X + (size_t)b * CIN * HW + pix;
    const float* wr = cw + co * CIN;

    float acc = 0.f;
#pragma unroll 8
    for (int ci = 0; ci < CIN; ++ci)
        acc += xb[(size_t)ci * HW] * wr[ci];

    float s = cg[co] / sqrtf(1.0f + BN_EPS);
    float v = acc * s + cb[co];
    v = v / (1.f + expf(-v));      // SiLU
    W1[idx] = v;
}

// ---------------- Kernel B: 3x3 conv (pad 1) + BN(eval) -> W2 [B][KOC][H][W] fp32
__global__ __launch_bounds__(256) void enc_kernel(
    const float* __restrict__ W1,
    const float* __restrict__ ew,
    const float* __restrict__ eg,
    const float* __restrict__ eb,
    float* __restrict__ W2o)
{
    int idx = blockIdx.x * blockDim.x + threadIdx.x;   // ((b*KOC+ko)*HW + pix)
    if (idx >= Bn * KOC * HW) return;
    int pix = idx & (HW - 1);
    int t   = idx >> 12;
    int ko  = t % KOC;
    int b   = t / KOC;
    int h = pix >> 6, w = pix & (Ww - 1);

    const float* wb = W1 + (size_t)b * CMID * HW;
    float acc = 0.f;

    for (int cm = 0; cm < CMID; ++cm) {
        const float* kw = ew + ((size_t)ko * CMID + cm) * 9;
        float k0 = kw[0], k1 = kw[1], k2 = kw[2];
        float k3 = kw[3], k4 = kw[4], k5 = kw[5];
        float k6 = kw[6], k7 = kw[7], k8 = kw[8];
        const float* p = wb + (size_t)cm * HW;

        int rm = h - 1, rp = h + 1;
        int cm1 = w - 1, cp1 = w + 1;
        bool rmv = (rm >= 0), rpv = (rp < Hh);
        bool clv = (cm1 >= 0), crv = (cp1 < Ww);

        const float* r0 = p + rm * Ww;
        const float* r1 = p + h  * Ww;
        const float* r2 = p + rp * Ww;

        if (rmv) {
            if (clv) acc += k0 * r0[cm1];
            acc += k1 * r0[w];
            if (crv) acc += k2 * r0[cp1];
        }
        if (clv) acc += k3 * r1[cm1];
        acc += k4 * r1[w];
        if (crv) acc += k5 * r1[cp1];
        if (rpv) {
            if (clv) acc += k6 * r2[cm1];
            acc += k7 * r2[w];
            if (crv) acc += k8 * r2[cp1];
        }
    }

    float s = eg[ko] / sqrtf(1.0f + BN_EPS);
    W2o[idx] = acc * s + eb[ko];
}

// ---------------- Kernel C: pixel-shuffle gather + softmax over 25
// Wsm layout: [b][h][w][sub][25] contiguous in k
__global__ __launch_bounds__(256) void softmax_kernel(
    const float* __restrict__ W2o,
    float* __restrict__ Wsm)
{
    int idx = blockIdx.x * blockDim.x + threadIdx.x;   // (b*HW+pix)*4 + sub
    if (idx >= Bn * HW * 4) return;
    int sub = idx & 3;
    int t   = idx >> 2;
    int pix = t & (HW - 1);
    int b   = t >> 12;

    const float* base = W2o + (size_t)b * KOC * HW + pix;
    float v[25];
    float m = -1e30f;
#pragma unroll
    for (int k = 0; k < 25; ++k) {
        v[k] = base[(size_t)(4 * k + sub) * HW];
        m = fmaxf(m, v[k]);
    }
    float sum = 0.f;
#pragma unroll
    for (int k = 0; k < 25; ++k) {
        v[k] = expf(v[k] - m);
        sum += v[k];
    }
    float inv = 1.f / sum;
    float* o = Wsm + (size_t)idx * 25;
#pragma unroll
    for (int k = 0; k < 25; ++k)
        o[k] = v[k] * inv;
}

// ---------------- Kernel D: CARAFE reassembly
// out[b][c][h'][w'] = sum_{ki,kj} Wsm[b,h,w,sub,ki*5+kj] * X[b,c,h+ki-2,w+kj-2]
// (parity fold: floor((h2-4+2*ki)/2) = h + ki - 2 for both parities of h2)
__global__ __launch_bounds__(256) void carafe_kernel(
    const float* __restrict__ X,
    const float* __restrict__ Wsm,
    float* __restrict__ out)
{
    int idx = blockIdx.x * blockDim.x + threadIdx.x;   // ((b*CIN+c)*HW2 + h2*W2 + w2)
    int w2 = idx & (W2d - 1);
    int h2 = (idx >> 7) & (H2 - 1);
    int t  = idx >> 14;
    int c  = t & (CIN - 1);
    int b  = t >> 7;

    int h = h2 >> 1, w = w2 >> 1;
    int sub = ((h2 & 1) << 1) | (w2 & 1);

    const float* wt = Wsm + ((((size_t)b * HW + h * Ww + w) * 4) + sub) * 25;
    const float* xc = X + ((size_t)b * CIN + c) * HW;

    float acc = 0.f;
#pragma unroll
    for (int ki = 0; ki < KUP; ++ki) {
        int r = h + ki - 2;
        if ((unsigned)r < (unsigned)Hh) {
            const float* row = xc + r * Ww;
#pragma unroll
            for (int kj = 0; kj < KUP; ++kj) {
                int cc = w + kj - 2;
                if ((unsigned)cc < (unsigned)Ww)
                    acc += wt[ki * 5 + kj] * row[cc];
            }
        }
    }
    out[idx] = acc;
}

extern "C" void kernel_launch(void* const* d_in, const int* in_sizes, int n_in,
                              void* d_out, int out_size, void* d_ws, size_t ws_size,
                              hipStream_t stream)
{
    const float* X  = (const float*)d_in[0];
    const float* cw = (const float*)d_in[1];
    const float* cg = (const float*)d_in[2];
    const float* cb = (const float*)d_in[3];
    const float* ew = (const float*)d_in[4];
    const float* eg = (const float*)d_in[5];
    const float* eb = (const float*)d_in[6];
    float* out = (float*)d_out;

    float* W1  = (float*)d_ws;                       // 4*64*4096   = 1,048,576 f
    float* W2o = W1  + (size_t)Bn * CMID * HW;       // 4*100*4096  = 1,638,400 f
    float* Wsm = W2o + (size_t)Bn * KOC  * HW;       // 4*4096*4*25 = 1,638,400 f

    comp_kernel   <<<Bn * CMID * HW / 256, 256, 0, stream>>>(X, cw, cg, cb, W1);
    enc_kernel    <<<Bn * KOC  * HW / 256, 256, 0, stream>>>(W1, ew, eg, eb, W2o);
    softmax_kernel<<<Bn * HW * 4  / 256, 256, 0, stream>>>(W2o, Wsm);
    carafe_kernel <<<Bn * CIN * HW2 / 256, 256, 0, stream>>>(X, Wsm, out);
}

// Round 3
// 228.174 us; speedup vs baseline: 3.4110x; 3.4110x over previous
//
#include <hip/hip_runtime.h>
#include <math.h>

#define Bn   4
#define CIN  128
#define Hh   64
#define Ww   64
#define HW   4096
#define CMID 64
#define KOC  100      // (scale*k_up)^2
#define H2   128
#define W2d  128
#define HW2  16384
#define KUP  5
#define BN_EPS 1e-5f
#define CCH  16       // channels per carafe thread (8 chunks of 16)

// ---------------- Kernel A: 1x1 conv + BN(eval) + SiLU -> W1 [B][CMID][H][W] fp32
__global__ __launch_bounds__(256) void comp_kernel(
    const float* __restrict__ X,
    const float* __restrict__ cw,
    const float* __restrict__ cg,
    const float* __restrict__ cb,
    float* __restrict__ W1)
{
    int idx = blockIdx.x * blockDim.x + threadIdx.x;   // ((b*CMID+co)*HW + pix)
    int pix = idx & (HW - 1);
    int t   = idx >> 12;
    int co  = t & (CMID - 1);
    int b   = t >> 6;

    const float* xb = X + (size_t)b * CIN * HW + pix;
    const float* wr = cw + co * CIN;

    float acc = 0.f;
#pragma unroll 8
    for (int ci = 0; ci < CIN; ++ci)
        acc += xb[(size_t)ci * HW] * wr[ci];

    float s = cg[co] / sqrtf(1.0f + BN_EPS);
    float v = acc * s + cb[co];
    v = v / (1.f + expf(-v));      // SiLU
    W1[idx] = v;
}

// ---------------- Kernel B: 3x3 conv (pad 1) + BN(eval) -> W2 [B][KOC][H][W] fp32
// Each thread computes a 4-tall h-strip for one (b,ko,w): 18 loads -> 36 FMA per cm.
__global__ __launch_bounds__(256) void enc_kernel(
    const float* __restrict__ W1,
    const float* __restrict__ ew,
    const float* __restrict__ eg,
    const float* __restrict__ eb,
    float* __restrict__ W2o)
{
    int gt = blockIdx.x * blockDim.x + threadIdx.x;    // ((b*KOC+ko)*16 + h4)*64 + w
    int w  = gt & 63;
    int h4 = (gt >> 6) & 15;
    int t  = gt >> 10;
    int ko = t % KOC;
    int b  = t / KOC;
    int h0 = h4 * 4;

    const float* wb = W1 + (size_t)b * CMID * HW;
    float acc0 = 0.f, acc1 = 0.f, acc2 = 0.f, acc3 = 0.f;

    for (int cm = 0; cm < CMID; ++cm) {
        const float* p = wb + (size_t)cm * HW;
        float v[6][3];
#pragma unroll
        for (int j = 0; j < 6; ++j) {
            int hr = h0 - 1 + j;
            int hc = hr < 0 ? 0 : (hr > 63 ? 63 : hr);
            const float* rp = p + hc * Ww;
            float lv = (w > 0)  ? rp[w - 1] : 0.f;
            float cv = rp[w];
            float rv = (w < 63) ? rp[w + 1] : 0.f;
            if ((unsigned)hr >= 64u) { lv = 0.f; cv = 0.f; rv = 0.f; }
            v[j][0] = lv; v[j][1] = cv; v[j][2] = rv;
        }
        const float* kw = ew + ((size_t)ko * CMID + cm) * 9;
        float k0 = kw[0], k1 = kw[1], k2 = kw[2];
        float k3 = kw[3], k4 = kw[4], k5 = kw[5];
        float k6 = kw[6], k7 = kw[7], k8 = kw[8];

        acc0 += k0*v[0][0] + k1*v[0][1] + k2*v[0][2]
              + k3*v[1][0] + k4*v[1][1] + k5*v[1][2]
              + k6*v[2][0] + k7*v[2][1] + k8*v[2][2];
        acc1 += k0*v[1][0] + k1*v[1][1] + k2*v[1][2]
              + k3*v[2][0] + k4*v[2][1] + k5*v[2][2]
              + k6*v[3][0] + k7*v[3][1] + k8*v[3][2];
        acc2 += k0*v[2][0] + k1*v[2][1] + k2*v[2][2]
              + k3*v[3][0] + k4*v[3][1] + k5*v[3][2]
              + k6*v[4][0] + k7*v[4][1] + k8*v[4][2];
        acc3 += k0*v[3][0] + k1*v[3][1] + k2*v[3][2]
              + k3*v[4][0] + k4*v[4][1] + k5*v[4][2]
              + k6*v[5][0] + k7*v[5][1] + k8*v[5][2];
    }

    float s  = eg[ko] / sqrtf(1.0f + BN_EPS);
    float bb = eb[ko];
    float* o = W2o + ((size_t)b * KOC + ko) * HW + h0 * Ww + w;
    o[0*Ww] = acc0 * s + bb;
    o[1*Ww] = acc1 * s + bb;
    o[2*Ww] = acc2 * s + bb;
    o[3*Ww] = acc3 * s + bb;
}

// ---------------- Kernel C: pixel-shuffle gather + softmax over 25
// Wsm layout: [b][h][w][sub][25] -> 100 contiguous floats per (b,h,w)
__global__ __launch_bounds__(256) void softmax_kernel(
    const float* __restrict__ W2o,
    float* __restrict__ Wsm)
{
    int idx = blockIdx.x * blockDim.x + threadIdx.x;   // (b*HW+pix)*4 + sub
    int sub = idx & 3;
    int t   = idx >> 2;
    int pix = t & (HW - 1);
    int b   = t >> 12;

    const float* base = W2o + (size_t)b * KOC * HW + pix;
    float v[25];
    float m = -1e30f;
#pragma unroll
    for (int k = 0; k < 25; ++k) {
        v[k] = base[(size_t)(4 * k + sub) * HW];
        m = fmaxf(m, v[k]);
    }
    float sum = 0.f;
#pragma unroll
    for (int k = 0; k < 25; ++k) {
        v[k] = expf(v[k] - m);
        sum += v[k];
    }
    float inv = 1.f / sum;
    float* o = Wsm + (size_t)idx * 25;
#pragma unroll
    for (int k = 0; k < 25; ++k)
        o[k] = v[k] * inv;
}

// ---------------- Kernel D: CARAFE reassembly (weights-in-registers)
// thread = (b,h,w, chunk-of-16-channels); holds all 100 weights (4 subs x 25)
// in VGPRs, loops channels: 25 shared X loads -> 4 outputs (100 FMA).
__global__ __launch_bounds__(256) void carafe_kernel(
    const float* __restrict__ X,
    const float* __restrict__ Wsm,
    float* __restrict__ out)
{
    int gt = blockIdx.x * blockDim.x + threadIdx.x;    // (chunk*Bn + b)*HW + h*64 + w
    int w  = gt & 63;
    int h  = (gt >> 6) & 63;
    int b  = (gt >> 12) & 3;
    int chunk = gt >> 14;                              // 0..7
    int c0 = chunk * CCH;

    // load 100 contiguous weights (4 subs x 25) as float4s
    float wt[100];
    const float* wp = Wsm + ((size_t)b * HW + h * Ww + w) * 100;
#pragma unroll
    for (int q = 0; q < 25; ++q)
        *(float4*)(wt + 4 * q) = ((const float4*)wp)[q];

    // per-tap plane offsets (clamped); zero weights at invalid taps
    int off[25];
#pragma unroll
    for (int ki = 0; ki < 5; ++ki) {
#pragma unroll
        for (int kj = 0; kj < 5; ++kj) {
            int k = ki * 5 + kj;
            int r = h + ki - 2, cc = w + kj - 2;
            bool valid = ((unsigned)r < 64u) && ((unsigned)cc < 64u);
            int rc = r < 0 ? 0 : (r > 63 ? 63 : r);
            int cx = cc < 0 ? 0 : (cc > 63 ? 63 : cc);
            off[k] = rc * Ww + cx;
            if (!valid) { wt[k] = 0.f; wt[25+k] = 0.f; wt[50+k] = 0.f; wt[75+k] = 0.f; }
        }
    }

    const float* xp = X + ((size_t)b * CIN + c0) * HW;
    float* o0 = out + ((size_t)b * CIN + c0) * HW2 + (2 * h) * W2d + 2 * w;

    for (int c = 0; c < CCH; ++c) {
        float x[25];
#pragma unroll
        for (int k = 0; k < 25; ++k) x[k] = xp[off[k]];
        float a0 = 0.f, a1 = 0.f, a2 = 0.f, a3 = 0.f;
#pragma unroll
        for (int k = 0; k < 25; ++k) {
            float xv = x[k];
            a0 += wt[k]      * xv;
            a1 += wt[25 + k] * xv;
            a2 += wt[50 + k] * xv;
            a3 += wt[75 + k] * xv;
        }
        *(float2*)o0          = make_float2(a0, a1);
        *(float2*)(o0 + W2d)  = make_float2(a2, a3);
        xp += HW;
        o0 += HW2;
    }
}

extern "C" void kernel_launch(void* const* d_in, const int* in_sizes, int n_in,
                              void* d_out, int out_size, void* d_ws, size_t ws_size,
                              hipStream_t stream)
{
    const float* X  = (const float*)d_in[0];
    const float* cw = (const float*)d_in[1];
    const float* cg = (const float*)d_in[2];
    const float* cb = (const float*)d_in[3];
    const float* ew = (const float*)d_in[4];
    const float* eg = (const float*)d_in[5];
    const float* eb = (const float*)d_in[6];
    float* out = (float*)d_out;

    float* W1  = (float*)d_ws;                       // 4*64*4096   = 1,048,576 f
    float* W2o = W1  + (size_t)Bn * CMID * HW;       // 4*100*4096  = 1,638,400 f
    float* Wsm = W2o + (size_t)Bn * KOC  * HW;       // 4*4096*100  = 1,638,400 f

    comp_kernel   <<<Bn * CMID * HW / 256, 256, 0, stream>>>(X, cw, cg, cb, W1);
    enc_kernel    <<<Bn * KOC * 16 * 64 / 256, 256, 0, stream>>>(W1, ew, eg, eb, W2o);
    softmax_kernel<<<Bn * HW * 4 / 256, 256, 0, stream>>>(W2o, Wsm);
    carafe_kernel <<<8 * Bn * HW / 256, 256, 0, stream>>>(X, Wsm, out);
}

// Round 4
// 177.878 us; speedup vs baseline: 4.3754x; 1.2828x over previous
//
#include <hip/hip_runtime.h>
#include <math.h>

#define Bn   4
#define CIN  128
#define Hh   64
#define Ww   64
#define HW   4096
#define CMID 64
#define KOC  100      // (scale*k_up)^2
#define H2   128
#define W2d  128
#define HW2  16384
#define KUP  5
#define BN_EPS 1e-5f
#define CCH  16       // channels per carafe thread (8 chunks of 16)

// ---------------- Kernel A: 1x1 conv + BN(eval) + SiLU -> W1 [B][CMID][H][W] fp32
// co-group of 8: one X load feeds 8 FMA; weights are block-uniform (scalar loads).
__global__ __launch_bounds__(256) void comp_kernel(
    const float* __restrict__ X,
    const float* __restrict__ cw,
    const float* __restrict__ cg,
    const float* __restrict__ cb,
    float* __restrict__ W1)
{
    int bid   = blockIdx.x;          // (b*8 + cog)*16 + pixhi
    int pixhi = bid & 15;
    int t     = bid >> 4;
    int cog   = t & 7;
    int b     = t >> 3;
    int pix   = pixhi * 256 + threadIdx.x;
    int co0   = cog * 8;

    const float* xb = X + (size_t)b * CIN * HW + pix;
    float acc[8] = {0.f, 0.f, 0.f, 0.f, 0.f, 0.f, 0.f, 0.f};

#pragma unroll 4
    for (int ci = 0; ci < CIN; ++ci) {
        float xv = xb[(size_t)ci * HW];
#pragma unroll
        for (int g = 0; g < 8; ++g)
            acc[g] += xv * cw[(size_t)(co0 + g) * CIN + ci];
    }

    float inv_s = rsqrtf(1.0f + BN_EPS);
#pragma unroll
    for (int g = 0; g < 8; ++g) {
        int co = co0 + g;
        float v = acc[g] * (cg[co] * inv_s) + cb[co];
        v = v / (1.f + expf(-v));    // SiLU
        W1[((size_t)b * CMID + co) * HW + pix] = v;
    }
}

// ---------------- Kernel B: 3x3 conv (pad 1) + BN(eval) -> W2 [B][KOC][H][W] fp32
// ko-group of 4 x h-strip of 4: 18 loads feed 144 FMA; weights block-uniform.
__global__ __launch_bounds__(256) void enc_kernel(
    const float* __restrict__ W1,
    const float* __restrict__ ew,
    const float* __restrict__ eg,
    const float* __restrict__ eb,
    float* __restrict__ W2o)
{
    int bid  = blockIdx.x;           // (b*25 + kg)*4 + h4hi   -> 400 blocks
    int h4hi = bid & 3;
    int t    = bid >> 2;
    int kg   = t % 25;
    int b    = t / 25;
    int tid  = threadIdx.x;
    int w    = tid & 63;
    int h4   = h4hi * 4 + (tid >> 6);
    int h0   = h4 * 4;
    int ko0  = kg * 4;

    const float* wb = W1 + (size_t)b * CMID * HW;
    float acc[4][4];                 // [ko_g][row]
#pragma unroll
    for (int g = 0; g < 4; ++g)
#pragma unroll
        for (int j = 0; j < 4; ++j) acc[g][j] = 0.f;

    for (int cm = 0; cm < CMID; ++cm) {
        const float* p = wb + (size_t)cm * HW;
        float v[6][3];
#pragma unroll
        for (int j = 0; j < 6; ++j) {
            int hr = h0 - 1 + j;
            int hc = hr < 0 ? 0 : (hr > 63 ? 63 : hr);
            const float* rp = p + hc * Ww;
            float lv = (w > 0)  ? rp[w - 1] : 0.f;
            float cv = rp[w];
            float rv = (w < 63) ? rp[w + 1] : 0.f;
            if ((unsigned)hr >= 64u) { lv = 0.f; cv = 0.f; rv = 0.f; }
            v[j][0] = lv; v[j][1] = cv; v[j][2] = rv;
        }

        const float* kwb = ew + ((size_t)ko0 * CMID + cm) * 9;
#pragma unroll
        for (int g = 0; g < 4; ++g) {
            const float* kw = kwb + (size_t)g * CMID * 9;
            float k0 = kw[0], k1 = kw[1], k2 = kw[2];
            float k3 = kw[3], k4 = kw[4], k5 = kw[5];
            float k6 = kw[6], k7 = kw[7], k8 = kw[8];
#pragma unroll
            for (int j = 0; j < 4; ++j)
                acc[g][j] += k0*v[j][0]   + k1*v[j][1]   + k2*v[j][2]
                           + k3*v[j+1][0] + k4*v[j+1][1] + k5*v[j+1][2]
                           + k6*v[j+2][0] + k7*v[j+2][1] + k8*v[j+2][2];
        }
    }

    float inv_s = rsqrtf(1.0f + BN_EPS);
#pragma unroll
    for (int g = 0; g < 4; ++g) {
        int ko = ko0 + g;
        float s  = eg[ko] * inv_s;
        float bb = eb[ko];
        float* o = W2o + ((size_t)b * KOC + ko) * HW + h0 * Ww + w;
#pragma unroll
        for (int j = 0; j < 4; ++j)
            o[j * Ww] = acc[g][j] * s + bb;
    }
}

// ---------------- Kernel C: pixel-shuffle gather + softmax over 25
// sub-major indexing: adjacent lanes read adjacent pixels (coalesced).
// Wsm layout: [b][h][w][sub][25] -> 100 contiguous floats per (b,h,w)
__global__ __launch_bounds__(256) void softmax_kernel(
    const float* __restrict__ W2o,
    float* __restrict__ Wsm)
{
    int idx = blockIdx.x * blockDim.x + threadIdx.x;   // ((b*4+sub)*HW + pix)
    int pix = idx & (HW - 1);
    int sub = (idx >> 12) & 3;
    int b   = idx >> 14;

    const float* base = W2o + (size_t)b * KOC * HW + pix;
    float v[25];
    float m = -1e30f;
#pragma unroll
    for (int k = 0; k < 25; ++k) {
        v[k] = base[(size_t)(4 * k + sub) * HW];
        m = fmaxf(m, v[k]);
    }
    float sum = 0.f;
#pragma unroll
    for (int k = 0; k < 25; ++k) {
        v[k] = expf(v[k] - m);
        sum += v[k];
    }
    float inv = 1.f / sum;
    float* o = Wsm + (((size_t)b * HW + pix) * 4 + sub) * 25;
#pragma unroll
    for (int k = 0; k < 25; ++k)
        o[k] = v[k] * inv;
}

// ---------------- Kernel D: CARAFE reassembly (weights-in-registers)
// thread = (b,h,w, chunk-of-16-channels); holds all 100 weights (4 subs x 25)
// in VGPRs, loops channels: 25 shared X loads -> 4 outputs (100 FMA).
// (parity fold: floor((h2-4+2*ki)/2) = h + ki - 2 for both parities of h2)
__global__ __launch_bounds__(256) void carafe_kernel(
    const float* __restrict__ X,
    const float* __restrict__ Wsm,
    float* __restrict__ out)
{
    int gt = blockIdx.x * blockDim.x + threadIdx.x;    // (chunk*Bn + b)*HW + h*64 + w
    int w  = gt & 63;
    int h  = (gt >> 6) & 63;
    int b  = (gt >> 12) & 3;
    int chunk = gt >> 14;                              // 0..7
    int c0 = chunk * CCH;

    float wt[100];
    const float* wp = Wsm + ((size_t)b * HW + h * Ww + w) * 100;
#pragma unroll
    for (int q = 0; q < 25; ++q)
        *(float4*)(wt + 4 * q) = ((const float4*)wp)[q];

    int off[25];
#pragma unroll
    for (int ki = 0; ki < 5; ++ki) {
#pragma unroll
        for (int kj = 0; kj < 5; ++kj) {
            int k = ki * 5 + kj;
            int r = h + ki - 2, cc = w + kj - 2;
            bool valid = ((unsigned)r < 64u) && ((unsigned)cc < 64u);
            int rc = r < 0 ? 0 : (r > 63 ? 63 : r);
            int cx = cc < 0 ? 0 : (cc > 63 ? 63 : cc);
            off[k] = rc * Ww + cx;
            if (!valid) { wt[k] = 0.f; wt[25+k] = 0.f; wt[50+k] = 0.f; wt[75+k] = 0.f; }
        }
    }

    const float* xp = X + ((size_t)b * CIN + c0) * HW;
    float* o0 = out + ((size_t)b * CIN + c0) * HW2 + (2 * h) * W2d + 2 * w;

    for (int c = 0; c < CCH; ++c) {
        float x[25];
#pragma unroll
        for (int k = 0; k < 25; ++k) x[k] = xp[off[k]];
        float a0 = 0.f, a1 = 0.f, a2 = 0.f, a3 = 0.f;
#pragma unroll
        for (int k = 0; k < 25; ++k) {
            float xv = x[k];
            a0 += wt[k]      * xv;
            a1 += wt[25 + k] * xv;
            a2 += wt[50 + k] * xv;
            a3 += wt[75 + k] * xv;
        }
        *(float2*)o0          = make_float2(a0, a1);
        *(float2*)(o0 + W2d)  = make_float2(a2, a3);
        xp += HW;
        o0 += HW2;
    }
}

extern "C" void kernel_launch(void* const* d_in, const int* in_sizes, int n_in,
                              void* d_out, int out_size, void* d_ws, size_t ws_size,
                              hipStream_t stream)
{
    const float* X  = (const float*)d_in[0];
    const float* cw = (const float*)d_in[1];
    const float* cg = (const float*)d_in[2];
    const float* cb = (const float*)d_in[3];
    const float* ew = (const float*)d_in[4];
    const float* eg = (const float*)d_in[5];
    const float* eb = (const float*)d_in[6];
    float* out = (float*)d_out;

    float* W1  = (float*)d_ws;                       // 4*64*4096   = 1,048,576 f
    float* W2o = W1  + (size_t)Bn * CMID * HW;       // 4*100*4096  = 1,638,400 f
    float* Wsm = W2o + (size_t)Bn * KOC  * HW;       // 4*4096*100  = 1,638,400 f

    comp_kernel   <<<Bn * 8 * 16, 256, 0, stream>>>(X, cw, cg, cb, W1);       // 512 blocks
    enc_kernel    <<<Bn * 25 * 4, 256, 0, stream>>>(W1, ew, eg, eb, W2o);     // 400 blocks
    softmax_kernel<<<Bn * 4 * HW / 256, 256, 0, stream>>>(W2o, Wsm);          // 256 blocks
    carafe_kernel <<<8 * Bn * HW / 256, 256, 0, stream>>>(X, Wsm, out);       // 512 blocks
}

// Round 5
// 162.930 us; speedup vs baseline: 4.7768x; 1.0917x over previous
//
#include <hip/hip_runtime.h>
#include <math.h>

#define Bn   4
#define CIN  128
#define Hh   64
#define Ww   64
#define HW   4096
#define CMID 64
#define KOC  100      // (scale*k_up)^2
#define H2   128
#define W2d  128
#define HW2  16384
#define KUP  5
#define BN_EPS 1e-5f
#define CCH  8        // channels per carafe thread (16 chunks of 8)

// ---------------- Kernel A: 1x1 conv + BN(eval) + SiLU -> W1 [B][CMID][H][W] fp32
// co-group of 4: one X load feeds 4 FMA; weights block-uniform (scalar loads).
__global__ __launch_bounds__(256) void comp_kernel(
    const float* __restrict__ X,
    const float* __restrict__ cw,
    const float* __restrict__ cg,
    const float* __restrict__ cb,
    float* __restrict__ W1)
{
    int bid   = blockIdx.x;          // (b*16 + cog)*16 + pixhi  -> 1024 blocks
    int pixhi = bid & 15;
    int t     = bid >> 4;
    int cog   = t & 15;
    int b     = t >> 4;
    int pix   = pixhi * 256 + threadIdx.x;
    int co0   = cog * 4;

    const float* xb = X + (size_t)b * CIN * HW + pix;
    float acc[4] = {0.f, 0.f, 0.f, 0.f};

#pragma unroll 8
    for (int ci = 0; ci < CIN; ++ci) {
        float xv = xb[(size_t)ci * HW];
#pragma unroll
        for (int g = 0; g < 4; ++g)
            acc[g] += xv * cw[(size_t)(co0 + g) * CIN + ci];
    }

    float inv_s = rsqrtf(1.0f + BN_EPS);
#pragma unroll
    for (int g = 0; g < 4; ++g) {
        int co = co0 + g;
        float v = acc[g] * (cg[co] * inv_s) + cb[co];
        v = v / (1.f + expf(-v));    // SiLU
        W1[((size_t)b * CMID + co) * HW + pix] = v;
    }
}

// ---------------- Kernel B: 3x3 conv (pad 1) + BN(eval) -> W2 [B][KOC][H][W] fp32
// ko-group of 4 x h-strip of 2: 12 loads feed 72 FMA; 800 blocks (3.1/CU).
__global__ __launch_bounds__(256) void enc_kernel(
    const float* __restrict__ W1,
    const float* __restrict__ ew,
    const float* __restrict__ eg,
    const float* __restrict__ eb,
    float* __restrict__ W2o)
{
    int bid  = blockIdx.x;           // (b*25 + kg)*8 + h8   -> 800 blocks
    int h8   = bid & 7;
    int t    = bid >> 3;
    int kg   = t % 25;
    int b    = t / 25;
    int tid  = threadIdx.x;
    int w    = tid & 63;
    int slot = tid >> 6;             // 0..3
    int h0   = h8 * 8 + slot * 2;    // rows h0, h0+1
    int ko0  = kg * 4;

    const float* wb = W1 + (size_t)b * CMID * HW;
    float acc[4][2];
#pragma unroll
    for (int g = 0; g < 4; ++g) { acc[g][0] = 0.f; acc[g][1] = 0.f; }

    for (int cm = 0; cm < CMID; ++cm) {
        const float* p = wb + (size_t)cm * HW;
        float v[4][3];
#pragma unroll
        for (int j = 0; j < 4; ++j) {
            int hr = h0 - 1 + j;
            int hc = hr < 0 ? 0 : (hr > 63 ? 63 : hr);
            const float* rp = p + hc * Ww;
            float lv = (w > 0)  ? rp[w - 1] : 0.f;
            float cv = rp[w];
            float rv = (w < 63) ? rp[w + 1] : 0.f;
            if ((unsigned)hr >= 64u) { lv = 0.f; cv = 0.f; rv = 0.f; }
            v[j][0] = lv; v[j][1] = cv; v[j][2] = rv;
        }

        const float* kwb = ew + ((size_t)ko0 * CMID + cm) * 9;
#pragma unroll
        for (int g = 0; g < 4; ++g) {
            const float* kw = kwb + (size_t)g * CMID * 9;   // block-uniform -> scalar
            float k0 = kw[0], k1 = kw[1], k2 = kw[2];
            float k3 = kw[3], k4 = kw[4], k5 = kw[5];
            float k6 = kw[6], k7 = kw[7], k8 = kw[8];
#pragma unroll
            for (int j = 0; j < 2; ++j)
                acc[g][j] += k0*v[j][0]   + k1*v[j][1]   + k2*v[j][2]
                           + k3*v[j+1][0] + k4*v[j+1][1] + k5*v[j+1][2]
                           + k6*v[j+2][0] + k7*v[j+2][1] + k8*v[j+2][2];
        }
    }

    float inv_s = rsqrtf(1.0f + BN_EPS);
#pragma unroll
    for (int g = 0; g < 4; ++g) {
        int ko = ko0 + g;
        float s  = eg[ko] * inv_s;
        float bb = eb[ko];
        float* o = W2o + ((size_t)b * KOC + ko) * HW + h0 * Ww + w;
        o[0]  = acc[g][0] * s + bb;
        o[Ww] = acc[g][1] * s + bb;
    }
}

// ---------------- Kernel C: pixel-shuffle gather + softmax over 25
// sub-major indexing: adjacent lanes read adjacent pixels (coalesced).
// Wsm layout: [b][h][w][sub][25] -> 100 contiguous floats per (b,h,w)
__global__ __launch_bounds__(256) void softmax_kernel(
    const float* __restrict__ W2o,
    float* __restrict__ Wsm)
{
    int idx = blockIdx.x * blockDim.x + threadIdx.x;   // ((b*4+sub)*HW + pix)
    int pix = idx & (HW - 1);
    int sub = (idx >> 12) & 3;
    int b   = idx >> 14;

    const float* base = W2o + (size_t)b * KOC * HW + pix;
    float v[25];
    float m = -1e30f;
#pragma unroll
    for (int k = 0; k < 25; ++k) {
        v[k] = base[(size_t)(4 * k + sub) * HW];
        m = fmaxf(m, v[k]);
    }
    float sum = 0.f;
#pragma unroll
    for (int k = 0; k < 25; ++k) {
        v[k] = expf(v[k] - m);
        sum += v[k];
    }
    float inv = 1.f / sum;
    float* o = Wsm + (((size_t)b * HW + pix) * 4 + sub) * 25;
#pragma unroll
    for (int k = 0; k < 25; ++k)
        o[k] = v[k] * inv;
}

// ---------------- Kernel D: CARAFE reassembly (weights-in-registers)
// thread = (b,h,w, chunk-of-8-channels); holds all 100 weights (4 subs x 25)
// in VGPRs, loops channels: 25 shared X loads -> 4 outputs (100 FMA).
// (parity fold: floor((h2-4+2*ki)/2) = h + ki - 2 for both parities of h2)
__global__ __launch_bounds__(256) void carafe_kernel(
    const float* __restrict__ X,
    const float* __restrict__ Wsm,
    float* __restrict__ out)
{
    int gt = blockIdx.x * blockDim.x + threadIdx.x;    // (chunk*Bn + b)*HW + h*64 + w
    int w  = gt & 63;
    int h  = (gt >> 6) & 63;
    int b  = (gt >> 12) & 3;
    int chunk = gt >> 14;                              // 0..15
    int c0 = chunk * CCH;

    float wt[100];
    const float* wp = Wsm + ((size_t)b * HW + h * Ww + w) * 100;
#pragma unroll
    for (int q = 0; q < 25; ++q)
        *(float4*)(wt + 4 * q) = ((const float4*)wp)[q];

    int off[25];
#pragma unroll
    for (int ki = 0; ki < 5; ++ki) {
#pragma unroll
        for (int kj = 0; kj < 5; ++kj) {
            int k = ki * 5 + kj;
            int r = h + ki - 2, cc = w + kj - 2;
            bool valid = ((unsigned)r < 64u) && ((unsigned)cc < 64u);
            int rc = r < 0 ? 0 : (r > 63 ? 63 : r);
            int cx = cc < 0 ? 0 : (cc > 63 ? 63 : cc);
            off[k] = rc * Ww + cx;
            if (!valid) { wt[k] = 0.f; wt[25+k] = 0.f; wt[50+k] = 0.f; wt[75+k] = 0.f; }
        }
    }

    const float* xp = X + ((size_t)b * CIN + c0) * HW;
    float* o0 = out + ((size_t)b * CIN + c0) * HW2 + (2 * h) * W2d + 2 * w;

    for (int c = 0; c < CCH; ++c) {
        float x[25];
#pragma unroll
        for (int k = 0; k < 25; ++k) x[k] = xp[off[k]];
        float a0 = 0.f, a1 = 0.f, a2 = 0.f, a3 = 0.f;
#pragma unroll
        for (int k = 0; k < 25; ++k) {
            float xv = x[k];
            a0 += wt[k]      * xv;
            a1 += wt[25 + k] * xv;
            a2 += wt[50 + k] * xv;
            a3 += wt[75 + k] * xv;
        }
        *(float2*)o0          = make_float2(a0, a1);
        *(float2*)(o0 + W2d)  = make_float2(a2, a3);
        xp += HW;
        o0 += HW2;
    }
}

extern "C" void kernel_launch(void* const* d_in, const int* in_sizes, int n_in,
                              void* d_out, int out_size, void* d_ws, size_t ws_size,
                              hipStream_t stream)
{
    const float* X  = (const float*)d_in[0];
    const float* cw = (const float*)d_in[1];
    const float* cg = (const float*)d_in[2];
    const float* cb = (const float*)d_in[3];
    const float* ew = (const float*)d_in[4];
    const float* eg = (const float*)d_in[5];
    const float* eb = (const float*)d_in[6];
    float* out = (float*)d_out;

    float* W1  = (float*)d_ws;                       // 4*64*4096   = 1,048,576 f
    float* W2o = W1  + (size_t)Bn * CMID * HW;       // 4*100*4096  = 1,638,400 f
    float* Wsm = W2o + (size_t)Bn * KOC  * HW;       // 4*4096*100  = 1,638,400 f

    comp_kernel   <<<Bn * 16 * 16, 256, 0, stream>>>(X, cw, cg, cb, W1);      // 1024 blocks
    enc_kernel    <<<Bn * 25 * 8, 256, 0, stream>>>(W1, ew, eg, eb, W2o);     // 800 blocks
    softmax_kernel<<<Bn * 4 * HW / 256, 256, 0, stream>>>(W2o, Wsm);          // 256 blocks
    carafe_kernel <<<16 * Bn * HW / 256, 256, 0, stream>>>(X, Wsm, out);      // 1024 blocks
}

// Round 6
// 159.437 us; speedup vs baseline: 4.8815x; 1.0219x over previous
//
#include <hip/hip_runtime.h>
#include <math.h>

#define Bn   4
#define CIN  128
#define Hh   64
#define Ww   64
#define HW   4096
#define CMID 64
#define KOC  100      // (scale*k_up)^2
#define H2   128
#define W2d  128
#define HW2  16384
#define KUP  5
#define BN_EPS 1e-5f
#define CCH  8        // channels per carafe thread (16 chunks of 8)

// Padded W1 plane: 66 rows (1-row zero halo top+bottom) x 64 cols
#define PROWS 66
#define PPLANE (PROWS * Ww)          // 4224 floats per (b,cm)

// ---------------- Kernel A: 1x1 conv + BN(eval) + SiLU -> W1p [B][CMID][66][64]
// thread = 4 consecutive pixels (float4) x 2 co. First 32768 threads also zero
// the halo rows (rows 0 and 65 of each plane).
__global__ __launch_bounds__(256) void comp_kernel(
    const float* __restrict__ X,
    const float* __restrict__ cw,
    const float* __restrict__ cg,
    const float* __restrict__ cb,
    float* __restrict__ W1p)
{
    int gt  = blockIdx.x * blockDim.x + threadIdx.x;   // 512*256 = 131072 threads
    int pg  = gt & 1023;                               // pixel group (4 px)
    int cog = (gt >> 10) & 31;                         // 32 groups of 2 co
    int b   = gt >> 15;
    int pix = pg * 4;
    int co0 = cog * 2;

    // zero halo rows: 4b x 64cm x 2rows x 64w = 32768 elements
    if (gt < Bn * CMID * 2 * Ww) {
        int wz  = gt & 63;
        int r01 = (gt >> 6) & 1;
        int cmz = (gt >> 7) & 63;
        int bz  = gt >> 13;
        W1p[((size_t)(bz * CMID + cmz) * PROWS + (r01 ? (PROWS - 1) : 0)) * Ww + wz] = 0.f;
    }

    const float* xb = X + (size_t)b * CIN * HW + pix;
    float4 acc0 = make_float4(0.f, 0.f, 0.f, 0.f);
    float4 acc1 = make_float4(0.f, 0.f, 0.f, 0.f);

#pragma unroll 4
    for (int ci = 0; ci < CIN; ++ci) {
        float4 xv = *(const float4*)(xb + (size_t)ci * HW);
        float w0 = cw[(size_t)co0 * CIN + ci];
        float w1 = cw[(size_t)(co0 + 1) * CIN + ci];
        acc0.x += xv.x * w0; acc0.y += xv.y * w0; acc0.z += xv.z * w0; acc0.w += xv.w * w0;
        acc1.x += xv.x * w1; acc1.y += xv.y * w1; acc1.z += xv.z * w1; acc1.w += xv.w * w1;
    }

    float inv_s = rsqrtf(1.0f + BN_EPS);
    int h = pix >> 6, w = pix & 63;
#pragma unroll
    for (int g = 0; g < 2; ++g) {
        int co = co0 + g;
        float s  = cg[co] * inv_s;
        float bb = cb[co];
        float4 a = g ? acc1 : acc0;
        float4 r;
        float v;
        v = a.x * s + bb; r.x = v / (1.f + expf(-v));
        v = a.y * s + bb; r.y = v / (1.f + expf(-v));
        v = a.z * s + bb; r.z = v / (1.f + expf(-v));
        v = a.w * s + bb; r.w = v / (1.f + expf(-v));
        *(float4*)(W1p + ((size_t)(b * CMID + co) * PROWS + h + 1) * Ww + w) = r;
    }
}

// ---------------- Kernel B: 3x3 conv (pad 1) + BN(eval) -> W2 [B][KOC][H][W]
// thread = 4 consecutive w x 1 h x 2 ko. Per cm: 9 float4 loads -> 72 FMA.
// Halo rows make h-boundary handling free; only w-edges need selects.
__global__ __launch_bounds__(256) void enc_kernel(
    const float* __restrict__ W1p,
    const float* __restrict__ ew,
    const float* __restrict__ eg,
    const float* __restrict__ eb,
    float* __restrict__ W2o)
{
    int bid = blockIdx.x;            // (b*50 + kg)*4 + h16 -> 800 blocks
    int h16 = bid & 3;
    int t   = bid >> 2;
    int kg  = t % 50;
    int b   = t / 50;
    int tid = threadIdx.x;
    int w16 = tid & 15;              // w0 = w16*4
    int h   = h16 * 16 + (tid >> 4);
    int w0  = w16 * 4;
    int ko0 = kg * 2;

    const float* wb = W1p + (size_t)b * CMID * PPLANE;
    float acc[2][4];
#pragma unroll
    for (int g = 0; g < 2; ++g)
#pragma unroll
        for (int i = 0; i < 4; ++i) acc[g][i] = 0.f;

    bool has_l = (w16 > 0), has_r = (w16 < 15);

    for (int cm = 0; cm < CMID; ++cm) {
        const float* p = wb + (size_t)cm * PPLANE;
        float row[3][6];             // [j][0]=w0-1, [1..4]=w0..w0+3, [5]=w0+4
#pragma unroll
        for (int j = 0; j < 3; ++j) {
            const float* rp = p + (size_t)(h + j) * Ww + w0;   // padded row h-1+j
            float4 L = *(const float4*)(rp - 4);
            float4 C = *(const float4*)(rp);
            float4 R = *(const float4*)(rp + 4);
            row[j][0] = has_l ? L.w : 0.f;
            row[j][1] = C.x; row[j][2] = C.y; row[j][3] = C.z; row[j][4] = C.w;
            row[j][5] = has_r ? R.x : 0.f;
        }

#pragma unroll
        for (int g = 0; g < 2; ++g) {
            const float* kw = ew + ((size_t)(ko0 + g) * CMID + cm) * 9;  // uniform
            float k0 = kw[0], k1 = kw[1], k2 = kw[2];
            float k3 = kw[3], k4 = kw[4], k5 = kw[5];
            float k6 = kw[6], k7 = kw[7], k8 = kw[8];
#pragma unroll
            for (int i = 0; i < 4; ++i)
                acc[g][i] += k0*row[0][i] + k1*row[0][i+1] + k2*row[0][i+2]
                           + k3*row[1][i] + k4*row[1][i+1] + k5*row[1][i+2]
                           + k6*row[2][i] + k7*row[2][i+1] + k8*row[2][i+2];
        }
    }

    float inv_s = rsqrtf(1.0f + BN_EPS);
#pragma unroll
    for (int g = 0; g < 2; ++g) {
        int ko = ko0 + g;
        float s  = eg[ko] * inv_s;
        float bb = eb[ko];
        float4 r = make_float4(acc[g][0]*s+bb, acc[g][1]*s+bb, acc[g][2]*s+bb, acc[g][3]*s+bb);
        *(float4*)(W2o + ((size_t)b * KOC + ko) * HW + h * Ww + w0) = r;
    }
}

// ---------------- Kernel C: softmax over 25 (pixel-shuffle-aware, plane layout)
// Reads W2o planes (ko = 4k+sub), writes Wsm in the SAME plane layout.
// Fully coalesced both directions.
__global__ __launch_bounds__(256) void softmax_kernel(
    const float* __restrict__ W2o,
    float* __restrict__ Wsm)
{
    int idx = blockIdx.x * blockDim.x + threadIdx.x;   // ((b*4+sub)*HW + pix)
    int pix = idx & (HW - 1);
    int sub = (idx >> 12) & 3;
    int b   = idx >> 14;

    const float* base = W2o + (size_t)b * KOC * HW + pix;
    float* o          = Wsm + (size_t)b * KOC * HW + pix;
    float v[25];
    float m = -1e30f;
#pragma unroll
    for (int k = 0; k < 25; ++k) {
        v[k] = base[(size_t)(4 * k + sub) * HW];
        m = fmaxf(m, v[k]);
    }
    float sum = 0.f;
#pragma unroll
    for (int k = 0; k < 25; ++k) {
        v[k] = expf(v[k] - m);
        sum += v[k];
    }
    float inv = 1.f / sum;
#pragma unroll
    for (int k = 0; k < 25; ++k)
        o[(size_t)(4 * k + sub) * HW] = v[k] * inv;
}

// ---------------- Kernel D: CARAFE reassembly (weights-in-registers)
// thread = (b,h,w, chunk-of-8-channels); 100 coalesced plane loads for weights,
// then per channel: 25 shared X loads -> 4 outputs (100 FMA).
// (parity fold: floor((h2-4+2*ki)/2) = h + ki - 2 for both parities of h2)
__global__ __launch_bounds__(256) void carafe_kernel(
    const float* __restrict__ X,
    const float* __restrict__ Wsm,
    float* __restrict__ out)
{
    int gt = blockIdx.x * blockDim.x + threadIdx.x;    // (chunk*Bn + b)*HW + h*64 + w
    int w  = gt & 63;
    int h  = (gt >> 6) & 63;
    int b  = (gt >> 12) & 3;
    int chunk = gt >> 14;                              // 0..15
    int c0 = chunk * CCH;
    int pix = h * Ww + w;

    // weights from planes: wt[sub*25+k] = Wsm[b][4k+sub][pix]  (coalesced)
    float wt[100];
    const float* wpb = Wsm + (size_t)b * KOC * HW + pix;
#pragma unroll
    for (int k = 0; k < 25; ++k) {
        wt[k]      = wpb[(size_t)(4 * k + 0) * HW];
        wt[25 + k] = wpb[(size_t)(4 * k + 1) * HW];
        wt[50 + k] = wpb[(size_t)(4 * k + 2) * HW];
        wt[75 + k] = wpb[(size_t)(4 * k + 3) * HW];
    }

    int off[25];
#pragma unroll
    for (int ki = 0; ki < 5; ++ki) {
#pragma unroll
        for (int kj = 0; kj < 5; ++kj) {
            int k = ki * 5 + kj;
            int r = h + ki - 2, cc = w + kj - 2;
            bool valid = ((unsigned)r < 64u) && ((unsigned)cc < 64u);
            int rc = r < 0 ? 0 : (r > 63 ? 63 : r);
            int cx = cc < 0 ? 0 : (cc > 63 ? 63 : cc);
            off[k] = rc * Ww + cx;
            if (!valid) { wt[k] = 0.f; wt[25+k] = 0.f; wt[50+k] = 0.f; wt[75+k] = 0.f; }
        }
    }

    const float* xp = X + ((size_t)b * CIN + c0) * HW;
    float* o0 = out + ((size_t)b * CIN + c0) * HW2 + (2 * h) * W2d + 2 * w;

    for (int c = 0; c < CCH; ++c) {
        float x[25];
#pragma unroll
        for (int k = 0; k < 25; ++k) x[k] = xp[off[k]];
        float a0 = 0.f, a1 = 0.f, a2 = 0.f, a3 = 0.f;
#pragma unroll
        for (int k = 0; k < 25; ++k) {
            float xv = x[k];
            a0 += wt[k]      * xv;
            a1 += wt[25 + k] * xv;
            a2 += wt[50 + k] * xv;
            a3 += wt[75 + k] * xv;
        }
        *(float2*)o0          = make_float2(a0, a1);
        *(float2*)(o0 + W2d)  = make_float2(a2, a3);
        xp += HW;
        o0 += HW2;
    }
}

extern "C" void kernel_launch(void* const* d_in, const int* in_sizes, int n_in,
                              void* d_out, int out_size, void* d_ws, size_t ws_size,
                              hipStream_t stream)
{
    const float* X  = (const float*)d_in[0];
    const float* cw = (const float*)d_in[1];
    const float* cg = (const float*)d_in[2];
    const float* cb = (const float*)d_in[3];
    const float* ew = (const float*)d_in[4];
    const float* eg = (const float*)d_in[5];
    const float* eb = (const float*)d_in[6];
    float* out = (float*)d_out;

    float* W1p = (float*)d_ws + 64;                  // guard for rp-4 underflow
    float* W2o = W1p + (size_t)Bn * CMID * PPLANE;   // 1,081,344 floats
    float* Wsm = W2o + (size_t)Bn * KOC * HW;        // 1,638,400 floats

    comp_kernel   <<<512, 256, 0, stream>>>(X, cw, cg, cb, W1p);
    enc_kernel    <<<Bn * 50 * 4, 256, 0, stream>>>(W1p, ew, eg, eb, W2o);   // 800 blocks
    softmax_kernel<<<Bn * 4 * HW / 256, 256, 0, stream>>>(W2o, Wsm);         // 256 blocks
    carafe_kernel <<<16 * Bn * HW / 256, 256, 0, stream>>>(X, Wsm, out);     // 1024 blocks
}